// Round 3
// baseline (270.953 us; speedup 1.0000x reference)
//
#include <hip/hip_runtime.h>

typedef short bf16x8 __attribute__((ext_vector_type(8)));
typedef float f32x4 __attribute__((ext_vector_type(4)));

#define D_DIM 256
#define K_CL  128
#define BM    64
#define MARGIN 0.05f

__device__ __forceinline__ unsigned short f2bf(float f) {
  unsigned int u = __float_as_uint(f);
  return (unsigned short)((u + 0x7FFFu + ((u >> 16) & 1u)) >> 16);
}
__device__ __forceinline__ float bf2f(unsigned short s) {
  return __uint_as_float(((unsigned int)s) << 16);
}

// numpy pairwise fp32 sum of p[i]*p[i], n=256: two 128-blocks, each with the
// 8-accumulator unrolled pattern; halves combined with one fp32 add.
// Contraction OFF: numpy rounds the multiply before summing.
__device__ float np_sumsq256(const float* __restrict__ p) {
#pragma clang fp contract(off)
  float tot = 0.f;
  for (int blk = 0; blk < 2; ++blk) {
    const float* a = p + blk * 128;
    float r[8];
#pragma unroll
    for (int j = 0; j < 8; ++j) r[j] = a[j] * a[j];
    for (int i = 8; i < 128; i += 8) {
#pragma unroll
      for (int j = 0; j < 8; ++j) r[j] = r[j] + a[i + j] * a[i + j];
    }
    const float s = ((r[0] + r[1]) + (r[2] + r[3])) + ((r[4] + r[5]) + (r[6] + r[7]));
    tot = blk ? (tot + s) : s;
  }
  return tot;
}

// numpy pairwise fp32 sum, n=128 (8-accumulator pattern).
__device__ float np_sum128(const float* __restrict__ a) {
#pragma clang fp contract(off)
  float r[8];
#pragma unroll
  for (int j = 0; j < 8; ++j) r[j] = a[j];
  for (int i = 8; i < 128; i += 8) {
#pragma unroll
    for (int j = 0; j < 8; ++j) r[j] = r[j] + a[i + j];
  }
  return ((r[0] + r[1]) + (r[2] + r[3])) + ((r[4] + r[5]) + (r[6] + r[7]));
}

// 8 waves/block, 64 rows/block, 128 clusters. Each wave owns 16 clusters
// (B hi/lo fragments in registers), z tile staged hi/lo in LDS (XOR-swizzled
// 16B chunks). Rows whose MFMA top-2 sq-distance gap < MARGIN are re-resolved
// in-block by EMULATING the numpy fp32 pipeline (incl. fp32 s_tmp
// quantization ties -> lowest index), since the reference argmax follows
// fp32-rounded s, not the true fp64 argmin.
extern "C" __global__ void __launch_bounds__(512)
k_main(const float* __restrict__ z, const float* __restrict__ cen,
       float* __restrict__ s_out, float* __restrict__ c_out)
{
  __shared__ __align__(16) unsigned short za_hi[BM * D_DIM];
  __shared__ __align__(16) unsigned short za_lo[BM * D_DIM];
  __shared__ float zsq[BM];
  __shared__ float csq[K_CL];
  __shared__ float psum[8][BM];
  __shared__ unsigned long long pm1[8][BM];
  __shared__ unsigned long long pm2[8][BM];
  __shared__ float rowinv[BM];
  __shared__ unsigned int amb_n;
  __shared__ unsigned char amb_rows[BM];
  __shared__ float zsq_np_sh;

  const int tid = threadIdx.x;
  const int w   = tid >> 6;      // wave 0..7
  const int l   = tid & 63;      // lane
  const int l15 = l & 15;
  const int g   = l >> 4;        // 4-lane-group of 16
  const int row0 = blockIdx.x * BM;

  if (tid == 0) amb_n = 0;

  // ---- B fragments (registers) + csq. Wave w owns clusters w*16..w*16+15.
  bf16x8 bhi[8], blo[8];
  {
    const int c = (w << 4) + l15;
    const float* crow = cen + (size_t)c * D_DIM;
    float cs = 0.f;
#pragma unroll
    for (int k = 0; k < 8; ++k) {
      const int d0 = k * 32 + g * 8;
      const float4 v0 = *(const float4*)(crow + d0);
      const float4 v1 = *(const float4*)(crow + d0 + 4);
      const float vv[8] = {v0.x, v0.y, v0.z, v0.w, v1.x, v1.y, v1.z, v1.w};
#pragma unroll
      for (int i = 0; i < 8; ++i) {
        const unsigned short h  = f2bf(vv[i]);
        const unsigned short lo = f2bf(vv[i] - bf2f(h));
        bhi[k][i] = (short)h;
        blo[k][i] = (short)lo;
        cs += vv[i] * vv[i];
      }
    }
    cs += __shfl_xor(cs, 16);
    cs += __shfl_xor(cs, 32);
    if (g == 0) csq[c] = cs;
  }

  // ---- stage z tile: wave w stages rows w*8..w*8+7.
#pragma unroll
  for (int i = 0; i < 8; ++i) {
    const int r = (w << 3) + i;
    const float4 v = *(const float4*)(z + (size_t)(row0 + r) * D_DIM + (l << 2));
    float ss = v.x * v.x + v.y * v.y + v.z * v.z + v.w * v.w;
#pragma unroll
    for (int m = 1; m < 64; m <<= 1) ss += __shfl_xor(ss, m);
    if (l == 0) zsq[r] = ss;
    const unsigned short h0 = f2bf(v.x), h1 = f2bf(v.y), h2 = f2bf(v.z), h3 = f2bf(v.w);
    const unsigned short q0 = f2bf(v.x - bf2f(h0)), q1 = f2bf(v.y - bf2f(h1)),
                         q2 = f2bf(v.z - bf2f(h2)), q3 = f2bf(v.w - bf2f(h3));
    const int boff = (r << 9) + ((((l >> 1) ^ (r & 31)) << 4) | ((l & 1) << 3));
    *(unsigned long long*)((char*)za_hi + boff) =
        (unsigned long long)h0 | ((unsigned long long)h1 << 16) |
        ((unsigned long long)h2 << 32) | ((unsigned long long)h3 << 48);
    *(unsigned long long*)((char*)za_lo + boff) =
        (unsigned long long)q0 | ((unsigned long long)q1 << 16) |
        ((unsigned long long)q2 << 32) | ((unsigned long long)q3 << 48);
  }
  __syncthreads();

  // ---- MFMA: dot = z_hi*c_hi + z_hi*c_lo + z_lo*c_hi, fp32 accum.
  f32x4 acc[4];
#pragma unroll
  for (int rt = 0; rt < 4; ++rt) acc[rt] = (f32x4){0.f, 0.f, 0.f, 0.f};
#pragma unroll
  for (int k = 0; k < 8; ++k) {
#pragma unroll
    for (int rt = 0; rt < 4; ++rt) {
      const int r = (rt << 4) + l15;
      const int boff = (r << 9) + ((((k << 2) + g) ^ (r & 31)) << 4);
      const bf16x8 ahi = *(const bf16x8*)((const char*)za_hi + boff);
      const bf16x8 alo = *(const bf16x8*)((const char*)za_lo + boff);
      acc[rt] = __builtin_amdgcn_mfma_f32_16x16x32_bf16(ahi, bhi[k], acc[rt], 0, 0, 0);
      acc[rt] = __builtin_amdgcn_mfma_f32_16x16x32_bf16(ahi, blo[k], acc[rt], 0, 0, 0);
      acc[rt] = __builtin_amdgcn_mfma_f32_16x16x32_bf16(alo, bhi[k], acc[rt], 0, 0, 0);
    }
  }

  // ---- epilogue: C/D layout row=(l>>4)*4+reg, col=l&15.
  const int col = (w << 4) + l15;
  const float cq = csq[col];
  float st[4][4];
#pragma unroll
  for (int rt = 0; rt < 4; ++rt) {
#pragma unroll
    for (int j = 0; j < 4; ++j) {
      const int r = (rt << 4) + (g << 2) + j;
      const float sq  = fmaxf(zsq[r] + cq - 2.0f * acc[rt][j], 0.0f);
      const float nrm = sqrtf(sq);
      const float t   = 1.0f / (1.0f + nrm);   // alpha=1: (1+norm)^-1
      st[rt][j] = t;
      unsigned long long m1 = (((unsigned long long)__float_as_uint(sq)) << 32) |
                              (unsigned int)col;
      unsigned long long m2 = ~0ull;
      float ssum = t;
#pragma unroll
      for (int m = 1; m <= 8; m <<= 1) {
        const unsigned long long o1 = __shfl_xor(m1, m);
        const unsigned long long o2 = __shfl_xor(m2, m);
        const unsigned long long mn = m1 < o1 ? m1 : o1;
        const unsigned long long mx = m1 < o1 ? o1 : m1;
        m1 = mn;
        const unsigned long long t2 = m2 < o2 ? m2 : o2;
        m2 = mx < t2 ? mx : t2;
        ssum += __shfl_xor(ssum, m);
      }
      if (l15 == 0) { psum[w][r] = ssum; pm1[w][r] = m1; pm2[w][r] = m2; }
    }
  }
  __syncthreads();

  // ---- cross-wave combine: wave0 lane r handles row r.
  if (w == 0) {
    float sum = 0.f;
    unsigned long long m1 = ~0ull, m2 = ~0ull;
#pragma unroll
    for (int i = 0; i < 8; ++i) {
      sum += psum[i][l];
      const unsigned long long a1 = pm1[i][l];
      const unsigned long long a2 = pm2[i][l];
      const unsigned long long mn = m1 < a1 ? m1 : a1;
      const unsigned long long mx = m1 < a1 ? a1 : m1;
      m1 = mn;
      const unsigned long long t2 = m2 < a2 ? m2 : a2;
      m2 = mx < t2 ? mx : t2;
    }
    rowinv[l] = 1.0f / sum;
    c_out[row0 + l] = (float)(unsigned int)(m1 & 0xFFFFFFFFull);
    const float d1 = __uint_as_float((unsigned int)(m1 >> 32));
    const float d2 = __uint_as_float((unsigned int)(m2 >> 32));
    if ((d2 - d1) < MARGIN) {
      const unsigned int idx = atomicAdd(&amb_n, 1u);
      amb_rows[idx] = (unsigned char)l;
    }
  }
  __syncthreads();

  // ---- write s = s_tmp / rowsum
#pragma unroll
  for (int rt = 0; rt < 4; ++rt) {
#pragma unroll
    for (int j = 0; j < 4; ++j) {
      const int r = (rt << 4) + (g << 2) + j;
      s_out[(size_t)(row0 + r) * K_CL + col] = st[rt][j] * rowinv[r];
    }
  }
  __syncthreads();

  // ---- numpy-fp32-emulating refinement for ambiguous rows (rare).
  unsigned int na = amb_n;
  if (na == 0) return;
  if (na > BM) na = BM;
  float* zrow   = &psum[0][0];          // 256 floats (reuse)
  float* stmp   = (float*)&pm1[0][0];   // 128 floats (reuse)
  float* csq_np = (float*)&pm2[0][0];   // 128 floats (reuse)
  if (tid < K_CL) csq_np[tid] = np_sumsq256(cen + (size_t)tid * D_DIM);
  for (unsigned int e = 0; e < na; ++e) {
    const int r = amb_rows[e];
    __syncthreads();   // csq_np ready / previous iteration's reads done
    if (tid < 64) {
      *(float4*)(zrow + tid * 4) =
          *(const float4*)(z + (size_t)(row0 + r) * D_DIM + tid * 4);
    }
    __syncthreads();
    if (tid == 0) zsq_np_sh = np_sumsq256(zrow);
    __syncthreads();
    if (tid < K_CL) {
      const float* crow = cen + (size_t)tid * D_DIM;
      double dacc = 0.0;
      for (int d = 0; d < D_DIM; ++d)
        dacc += (double)zrow[d] * (double)crow[d];
      {
#pragma clang fp contract(off)
        const float dotf = (float)dacc;                        // ~sgemm, CR
        const float sq   = (zsq_np_sh + csq_np[tid]) - 2.0f * dotf;
        const float nrm  = sqrtf(fmaxf(sq, 0.0f));
        stmp[tid] = 1.0f / (1.0f + nrm);                       // np pow -1 fast path
      }
    }
    __syncthreads();
    if (tid == 0) {
#pragma clang fp contract(off)
      const float sum = np_sum128(stmp);
      int best = 0;
      float bs = stmp[0] / sum;
      for (int i = 1; i < K_CL; ++i) {
        const float si = stmp[i] / sum;
        if (si > bs) { bs = si; best = i; }   // strict >: first-index wins ties
      }
      c_out[row0 + r] = (float)best;
    }
  }
}

extern "C" void kernel_launch(void* const* d_in, const int* in_sizes, int n_in,
                              void* d_out, int out_size, void* d_ws, size_t ws_size,
                              hipStream_t stream) {
  const float* z   = (const float*)d_in[0];
  const float* cen = (const float*)d_in[1];
  const int M = in_sizes[0] / D_DIM;   // 131072
  float* s_out = (float*)d_out;
  float* c_out = s_out + (size_t)M * K_CL;

  hipLaunchKernelGGL(k_main, dim3(M / BM), dim3(512), 0, stream,
                     z, cen, s_out, c_out);
}

// Round 4
// 213.588 us; speedup vs baseline: 1.2686x; 1.2686x over previous
//
#include <hip/hip_runtime.h>

typedef short bf16x8 __attribute__((ext_vector_type(8)));
typedef float f32x4 __attribute__((ext_vector_type(4)));
typedef unsigned int u32x4 __attribute__((ext_vector_type(4)));

#define D_DIM 256
#define K_CL  128
#define BM    64
#define MARGIN 0.05f

__device__ __forceinline__ unsigned cvtpk(float a, float b) {
  unsigned r;
  asm("v_cvt_pk_bf16_f32 %0, %1, %2" : "=v"(r) : "v"(a), "v"(b));
  return r;  // r[15:0]=bf16(a), r[31:16]=bf16(b)
}
__device__ __forceinline__ float u2f_lo(unsigned p) {        // bf2f of low half
  return __uint_as_float(p << 16);
}
__device__ __forceinline__ float u2f_hi(unsigned p) {        // bf2f of high half
  return __uint_as_float(p & 0xFFFF0000u);
}

// numpy pairwise fp32 sum of p[i]*p[i], n=256 (verified refine path, round 3).
__device__ float np_sumsq256(const float* __restrict__ p) {
#pragma clang fp contract(off)
  float tot = 0.f;
  for (int blk = 0; blk < 2; ++blk) {
    const float* a = p + blk * 128;
    float r[8];
#pragma unroll
    for (int j = 0; j < 8; ++j) r[j] = a[j] * a[j];
    for (int i = 8; i < 128; i += 8) {
#pragma unroll
      for (int j = 0; j < 8; ++j) r[j] = r[j] + a[i + j] * a[i + j];
    }
    const float s = ((r[0] + r[1]) + (r[2] + r[3])) + ((r[4] + r[5]) + (r[6] + r[7]));
    tot = blk ? (tot + s) : s;
  }
  return tot;
}

// numpy pairwise fp32 sum, n=128.
__device__ float np_sum128(const float* __restrict__ a) {
#pragma clang fp contract(off)
  float r[8];
#pragma unroll
  for (int j = 0; j < 8; ++j) r[j] = a[j];
  for (int i = 8; i < 128; i += 8) {
#pragma unroll
    for (int j = 0; j < 8; ++j) r[j] = r[j] + a[i + j];
  }
  return ((r[0] + r[1]) + (r[2] + r[3])) + ((r[4] + r[5]) + (r[6] + r[7]));
}

// 8 waves/block, 64 rows/block, 128 clusters. Wave w owns clusters w*16..+15
// (B hi/lo fragments in regs, packed via v_cvt_pk_bf16_f32); z tile hi/lo in
// LDS, XOR-swizzled 16B chunks (0 bank conflicts measured). Argmin tracked as
// 32-bit key = (sq_bits & ~0x7F) | col; rows with top-2 gap < MARGIN get the
// numpy-fp32-emulating in-block refine (unchanged from passing round 3).
extern "C" __global__ void __launch_bounds__(512)
k_main(const float* __restrict__ z, const float* __restrict__ cen,
       float* __restrict__ s_out, float* __restrict__ c_out)
{
  __shared__ __align__(16) unsigned short za_hi[BM * D_DIM];
  __shared__ __align__(16) unsigned short za_lo[BM * D_DIM];
  __shared__ float zsq[BM];
  __shared__ float csq[K_CL];
  __shared__ float psum[8][BM];
  __shared__ unsigned int pm1u[8][BM];
  __shared__ unsigned int pm2u[8][BM];
  __shared__ float rowinv[BM];
  __shared__ unsigned int amb_n;
  __shared__ unsigned char amb_rows[BM];
  __shared__ float zsq_np_sh;

  const int tid = threadIdx.x;
  const int w   = tid >> 6;
  const int l   = tid & 63;
  const int l15 = l & 15;
  const int g   = l >> 4;
  const int row0 = blockIdx.x * BM;

  if (tid == 0) amb_n = 0;

  // ---- B fragments + csq. mfma B layout: lane l holds B[k=(l>>4)*8+i][n=l&15].
  bf16x8 bhi[8], blo[8];
  {
    const int c = (w << 4) + l15;
    const float* crow = cen + (size_t)c * D_DIM;
    float cs = 0.f;
#pragma unroll
    for (int k = 0; k < 8; ++k) {
      const int d0 = k * 32 + g * 8;
      const float4 v0 = *(const float4*)(crow + d0);
      const float4 v1 = *(const float4*)(crow + d0 + 4);
      const unsigned p0 = cvtpk(v0.x, v0.y), p1 = cvtpk(v0.z, v0.w);
      const unsigned p2 = cvtpk(v1.x, v1.y), p3 = cvtpk(v1.z, v1.w);
      const unsigned q0 = cvtpk(v0.x - u2f_lo(p0), v0.y - u2f_hi(p0));
      const unsigned q1 = cvtpk(v0.z - u2f_lo(p1), v0.w - u2f_hi(p1));
      const unsigned q2 = cvtpk(v1.x - u2f_lo(p2), v1.y - u2f_hi(p2));
      const unsigned q3 = cvtpk(v1.z - u2f_lo(p3), v1.w - u2f_hi(p3));
      bhi[k] = __builtin_bit_cast(bf16x8, (u32x4){p0, p1, p2, p3});
      blo[k] = __builtin_bit_cast(bf16x8, (u32x4){q0, q1, q2, q3});
      cs += v0.x * v0.x + v0.y * v0.y + v0.z * v0.z + v0.w * v0.w;
      cs += v1.x * v1.x + v1.y * v1.y + v1.z * v1.z + v1.w * v1.w;
    }
    cs += __shfl_xor(cs, 16);
    cs += __shfl_xor(cs, 32);
    if (g == 0) csq[c] = cs;
  }

  // ---- stage z tile: wave w stages rows w*8..w*8+7.
#pragma unroll
  for (int i = 0; i < 8; ++i) {
    const int r = (w << 3) + i;
    const float4 v = *(const float4*)(z + (size_t)(row0 + r) * D_DIM + (l << 2));
    float ss = v.x * v.x + v.y * v.y + v.z * v.z + v.w * v.w;
#pragma unroll
    for (int m = 1; m < 64; m <<= 1) ss += __shfl_xor(ss, m);
    if (l == 0) zsq[r] = ss;
    const unsigned p0 = cvtpk(v.x, v.y), p1 = cvtpk(v.z, v.w);
    const unsigned q0 = cvtpk(v.x - u2f_lo(p0), v.y - u2f_hi(p0));
    const unsigned q1 = cvtpk(v.z - u2f_lo(p1), v.w - u2f_hi(p1));
    const int boff = (r << 9) + ((((l >> 1) ^ (r & 31)) << 4) | ((l & 1) << 3));
    *(uint2*)((char*)za_hi + boff) = make_uint2(p0, p1);
    *(uint2*)((char*)za_lo + boff) = make_uint2(q0, q1);
  }
  __syncthreads();

  // ---- MFMA: dot = z_hi*c_hi + z_hi*c_lo + z_lo*c_hi, fp32 accum.
  f32x4 acc[4];
#pragma unroll
  for (int rt = 0; rt < 4; ++rt) acc[rt] = (f32x4){0.f, 0.f, 0.f, 0.f};
#pragma unroll
  for (int k = 0; k < 8; ++k) {
#pragma unroll
    for (int rt = 0; rt < 4; ++rt) {
      const int r = (rt << 4) + l15;
      const int boff = (r << 9) + ((((k << 2) + g) ^ (r & 31)) << 4);
      const bf16x8 ahi = *(const bf16x8*)((const char*)za_hi + boff);
      const bf16x8 alo = *(const bf16x8*)((const char*)za_lo + boff);
      acc[rt] = __builtin_amdgcn_mfma_f32_16x16x32_bf16(ahi, bhi[k], acc[rt], 0, 0, 0);
      acc[rt] = __builtin_amdgcn_mfma_f32_16x16x32_bf16(ahi, blo[k], acc[rt], 0, 0, 0);
      acc[rt] = __builtin_amdgcn_mfma_f32_16x16x32_bf16(alo, bhi[k], acc[rt], 0, 0, 0);
    }
  }

  // ---- epilogue: C/D layout row=(l>>4)*4+reg, col=l&15. 32-bit keys.
  const int col = (w << 4) + l15;
  const float cq = csq[col];
  float st[4][4];
#pragma unroll
  for (int rt = 0; rt < 4; ++rt) {
#pragma unroll
    for (int j = 0; j < 4; ++j) {
      const int r = (rt << 4) + (g << 2) + j;
      const float sq  = fmaxf(fmaf(-2.0f, acc[rt][j], zsq[r] + cq), 0.0f);
      const float nrm = __builtin_amdgcn_sqrtf(sq);
      const float t   = __builtin_amdgcn_rcpf(1.0f + nrm);   // alpha=1
      st[rt][j] = t;
      unsigned m1 = (__float_as_uint(sq) & 0xFFFFFF80u) | (unsigned)col;
      unsigned m2 = 0xFFFFFFFFu;
      float ssum = t;
#pragma unroll
      for (int m = 1; m <= 8; m <<= 1) {
        const unsigned o1 = __shfl_xor(m1, m);
        const unsigned o2 = __shfl_xor(m2, m);
        ssum += __shfl_xor(ssum, m);
        const unsigned mn = min(m1, o1), mx = max(m1, o1);
        m1 = mn;
        m2 = min(mx, min(m2, o2));
      }
      if (l15 == 0) { psum[w][r] = ssum; pm1u[w][r] = m1; pm2u[w][r] = m2; }
    }
  }
  __syncthreads();

  // ---- cross-wave combine: wave0 lane r handles row r.
  if (w == 0) {
    float sum = 0.f;
    unsigned m1 = 0xFFFFFFFFu, m2 = 0xFFFFFFFFu;
#pragma unroll
    for (int i = 0; i < 8; ++i) {
      sum += psum[i][l];
      const unsigned a1 = pm1u[i][l];
      const unsigned a2 = pm2u[i][l];
      const unsigned mn = min(m1, a1), mx = max(m1, a1);
      m1 = mn;
      m2 = min(mx, min(m2, a2));
    }
    rowinv[l] = __builtin_amdgcn_rcpf(sum);
    c_out[row0 + l] = (float)(m1 & 0x7Fu);
    const float d1 = __uint_as_float(m1 & 0xFFFFFF80u);
    const float d2 = __uint_as_float(m2 & 0xFFFFFF80u);
    if ((d2 - d1) < MARGIN) {
      const unsigned int idx = atomicAdd(&amb_n, 1u);
      amb_rows[idx] = (unsigned char)l;
    }
  }
  __syncthreads();

  // ---- write s = s_tmp / rowsum
#pragma unroll
  for (int rt = 0; rt < 4; ++rt) {
#pragma unroll
    for (int j = 0; j < 4; ++j) {
      const int r = (rt << 4) + (g << 2) + j;
      s_out[(size_t)(row0 + r) * K_CL + col] = st[rt][j] * rowinv[r];
    }
  }
  __syncthreads();

  // ---- numpy-fp32-emulating refinement for ambiguous rows (rare).
  unsigned int na = amb_n;
  if (na == 0) return;
  if (na > BM) na = BM;
  float* zrow   = &psum[0][0];           // 256 floats (reuse)
  float* stmp   = (float*)&pm1u[0][0];   // 128 floats (reuse)
  float* csq_np = (float*)&pm2u[0][0];   // 128 floats (reuse)
  if (tid < K_CL) csq_np[tid] = np_sumsq256(cen + (size_t)tid * D_DIM);
  for (unsigned int e = 0; e < na; ++e) {
    const int r = amb_rows[e];
    __syncthreads();   // csq_np ready / previous iteration's reads done
    if (tid < 64) {
      *(float4*)(zrow + tid * 4) =
          *(const float4*)(z + (size_t)(row0 + r) * D_DIM + tid * 4);
    }
    __syncthreads();
    if (tid == 0) zsq_np_sh = np_sumsq256(zrow);
    __syncthreads();
    if (tid < K_CL) {
      const float* crow = cen + (size_t)tid * D_DIM;
      double dacc = 0.0;
      for (int d = 0; d < D_DIM; ++d)
        dacc += (double)zrow[d] * (double)crow[d];
      {
#pragma clang fp contract(off)
        const float dotf = (float)dacc;                        // ~sgemm, CR
        const float sq   = (zsq_np_sh + csq_np[tid]) - 2.0f * dotf;
        const float nrm  = sqrtf(fmaxf(sq, 0.0f));
        stmp[tid] = 1.0f / (1.0f + nrm);                       // np pow -1 fast path
      }
    }
    __syncthreads();
    if (tid == 0) {
#pragma clang fp contract(off)
      const float sum = np_sum128(stmp);
      int best = 0;
      float bs = stmp[0] / sum;
      for (int i = 1; i < K_CL; ++i) {
        const float si = stmp[i] / sum;
        if (si > bs) { bs = si; best = i; }   // strict >: first-index wins ties
      }
      c_out[row0 + r] = (float)best;
    }
  }
}

extern "C" void kernel_launch(void* const* d_in, const int* in_sizes, int n_in,
                              void* d_out, int out_size, void* d_ws, size_t ws_size,
                              hipStream_t stream) {
  const float* z   = (const float*)d_in[0];
  const float* cen = (const float*)d_in[1];
  const int M = in_sizes[0] / D_DIM;   // 131072
  float* s_out = (float*)d_out;
  float* c_out = s_out + (size_t)M * K_CL;

  hipLaunchKernelGGL(k_main, dim3(M / BM), dim3(512), 0, stream,
                     z, cen, s_out, c_out);
}

// Round 5
// 145.132 us; speedup vs baseline: 1.8669x; 1.4717x over previous
//
#include <hip/hip_runtime.h>

typedef _Float16 f16x8 __attribute__((ext_vector_type(8)));
typedef _Float16 f16x2 __attribute__((ext_vector_type(2)));
typedef float f32x4 __attribute__((ext_vector_type(4)));
typedef unsigned int u32x4 __attribute__((ext_vector_type(4)));

#define D_DIM 256
#define K_CL  128
#define BM    64
#define KPAD  132          // key row stride (u32), 132*4B: 2-way-max write conflicts
#define MARGIN 0.1f

__device__ __forceinline__ unsigned pkf16(float a, float b) {
  return __builtin_bit_cast(unsigned, __builtin_amdgcn_cvt_pkrtz(a, b));
}

// numpy pairwise fp32 sum of p[i]*p[i], n=256 (verified refine path, round 3).
__device__ float np_sumsq256(const float* __restrict__ p) {
#pragma clang fp contract(off)
  float tot = 0.f;
  for (int blk = 0; blk < 2; ++blk) {
    const float* a = p + blk * 128;
    float r[8];
#pragma unroll
    for (int j = 0; j < 8; ++j) r[j] = a[j] * a[j];
    for (int i = 8; i < 128; i += 8) {
#pragma unroll
      for (int j = 0; j < 8; ++j) r[j] = r[j] + a[i + j] * a[i + j];
    }
    const float s = ((r[0] + r[1]) + (r[2] + r[3])) + ((r[4] + r[5]) + (r[6] + r[7]));
    tot = blk ? (tot + s) : s;
  }
  return tot;
}

// numpy pairwise fp32 sum, n=128.
__device__ float np_sum128(const float* __restrict__ a) {
#pragma clang fp contract(off)
  float r[8];
#pragma unroll
  for (int j = 0; j < 8; ++j) r[j] = a[j];
  for (int i = 8; i < 128; i += 8) {
#pragma unroll
    for (int j = 0; j < 8; ++j) r[j] = r[j] + a[i + j];
  }
  return ((r[0] + r[1]) + (r[2] + r[3])) + ((r[4] + r[5]) + (r[6] + r[7]));
}

// 8 waves/block, 64 rows, 128 clusters. Single fp16 MFMA path (error sigma
// ~0.01 in sq-dist, covered by MARGIN=0.1 refine). z tile fp16 in LDS
// (XOR-swizzled 16B chunks), keys written to an LDS buffer OVERLAYING the z
// tile (barrier-separated), one reader pass does two-smallest+rowsum.
extern "C" __global__ void __launch_bounds__(512)
k_main(const float* __restrict__ z, const float* __restrict__ cen,
       float* __restrict__ s_out, float* __restrict__ c_out)
{
  __shared__ __align__(16) unsigned char pool[BM * KPAD * 4];  // z16(32KB) / keys / refine
  __shared__ float zsq[BM];
  __shared__ float csq[K_CL];
  __shared__ float rowinv[BM];
  __shared__ unsigned int amb_n;
  __shared__ unsigned char amb_rows[BM];
  __shared__ float zsq_np_sh;

  const int tid = threadIdx.x;
  const int w   = tid >> 6;
  const int l   = tid & 63;
  const int l15 = l & 15;
  const int g   = l >> 4;
  const int row0 = blockIdx.x * BM;

  if (tid == 0) amb_n = 0;

  // ---- B fragments + csq. Wave w owns clusters w*16..+15.
  // mfma_f32_16x16x32_f16 B layout: lane holds B[k=(l>>4)*8+i][n=l&15].
  f16x8 bf[8];
  {
    const int c = (w << 4) + l15;
    const float* crow = cen + (size_t)c * D_DIM;
    float cs = 0.f;
#pragma unroll
    for (int k = 0; k < 8; ++k) {
      const int d0 = k * 32 + g * 8;
      const float4 v0 = *(const float4*)(crow + d0);
      const float4 v1 = *(const float4*)(crow + d0 + 4);
      bf[k] = __builtin_bit_cast(f16x8, (u32x4){pkf16(v0.x, v0.y), pkf16(v0.z, v0.w),
                                                pkf16(v1.x, v1.y), pkf16(v1.z, v1.w)});
      cs += v0.x * v0.x + v0.y * v0.y + v0.z * v0.z + v0.w * v0.w;
      cs += v1.x * v1.x + v1.y * v1.y + v1.z * v1.z + v1.w * v1.w;
    }
    cs += __shfl_xor(cs, 16);
    cs += __shfl_xor(cs, 32);
    if (g == 0) csq[c] = cs;
  }

  // ---- stage z tile (fp16): wave w stages rows w*8..w*8+7.
#pragma unroll
  for (int i = 0; i < 8; ++i) {
    const int r = (w << 3) + i;
    const float4 v = *(const float4*)(z + (size_t)(row0 + r) * D_DIM + (l << 2));
    float ss = v.x * v.x + v.y * v.y + v.z * v.z + v.w * v.w;
#pragma unroll
    for (int m = 1; m < 64; m <<= 1) ss += __shfl_xor(ss, m);
    if (l == 0) zsq[r] = ss;
    // row = 512B = 32 chunks of 16B; chunk (l>>1), half (l&1); XOR-swizzle by row.
    const int boff = (r << 9) + ((((l >> 1) ^ (r & 31)) << 4) | ((l & 1) << 3));
    *(uint2*)(pool + boff) = make_uint2(pkf16(v.x, v.y), pkf16(v.z, v.w));
  }
  __syncthreads();

  // ---- MFMA: 8 k-steps x 4 row-tiles, fp32 accum.
  f32x4 acc[4];
#pragma unroll
  for (int rt = 0; rt < 4; ++rt) acc[rt] = (f32x4){0.f, 0.f, 0.f, 0.f};
#pragma unroll
  for (int k = 0; k < 8; ++k) {
#pragma unroll
    for (int rt = 0; rt < 4; ++rt) {
      const int r = (rt << 4) + l15;   // A layout: lane holds A[m=l&15][k=(l>>4)*8+i]
      const int boff = (r << 9) + ((((k << 2) + g) ^ (r & 31)) << 4);
      const f16x8 af = *(const f16x8*)(pool + boff);
      acc[rt] = __builtin_amdgcn_mfma_f32_16x16x32_f16(af, bf[k], acc[rt], 0, 0, 0);
    }
  }
  __syncthreads();   // all waves done reading z16 before keys overwrite pool

  // ---- compute s_tmp + write keys. C/D layout: row=(l>>4)*4+reg, col=l&15.
  unsigned* keybuf = (unsigned*)pool;
  const int col = (w << 4) + l15;
  const float cq = csq[col];
  float st[4][4];
#pragma unroll
  for (int rt = 0; rt < 4; ++rt) {
#pragma unroll
    for (int j = 0; j < 4; ++j) {
      const int r = (rt << 4) + (g << 2) + j;
      const float sq  = fmaxf(fmaf(-2.0f, acc[rt][j], zsq[r] + cq), 0.0f);
      st[rt][j] = __builtin_amdgcn_rcpf(1.0f + __builtin_amdgcn_sqrtf(sq));
      keybuf[r * KPAD + col] = (__float_as_uint(sq) & 0xFFFFFF80u) | (unsigned)col;
    }
  }
  __syncthreads();

  // ---- reader pass: 8 threads/row, 16 keys each; two-smallest + rowsum.
  {
    const int rr = tid >> 3;
    const unsigned* kp = keybuf + rr * KPAD + ((tid & 7) << 4);
    u32x4 kv[4];
#pragma unroll
    for (int q = 0; q < 4; ++q) kv[q] = *(const u32x4*)(kp + (q << 2));
    unsigned m1 = 0xFFFFFFFFu, m2 = 0xFFFFFFFFu;
    float sum = 0.f;
#pragma unroll
    for (int q = 0; q < 4; ++q) {
#pragma unroll
      for (int e = 0; e < 4; ++e) {
        const unsigned u = kv[q][e];
        const unsigned mn = min(m1, u), mx = max(m1, u);
        m1 = mn;
        m2 = min(m2, mx);
        sum += __builtin_amdgcn_rcpf(
            1.0f + __builtin_amdgcn_sqrtf(__uint_as_float(u & 0xFFFFFF80u)));
      }
    }
#pragma unroll
    for (int m = 1; m <= 4; m <<= 1) {
      const unsigned o1 = __shfl_xor(m1, m);
      const unsigned o2 = __shfl_xor(m2, m);
      sum += __shfl_xor(sum, m);
      const unsigned mn = min(m1, o1), mx = max(m1, o1);
      m1 = mn;
      m2 = min(mx, min(m2, o2));
    }
    if ((tid & 7) == 0) {
      rowinv[rr] = __builtin_amdgcn_rcpf(sum);
      c_out[row0 + rr] = (float)(m1 & 0x7Fu);
      const float d1 = __uint_as_float(m1 & 0xFFFFFF80u);
      const float d2 = __uint_as_float(m2 & 0xFFFFFF80u);
      if ((d2 - d1) < MARGIN) {
        const unsigned idx = atomicAdd(&amb_n, 1u);
        amb_rows[idx] = (unsigned char)rr;
      }
    }
  }
  __syncthreads();

  // ---- write s = s_tmp / rowsum
#pragma unroll
  for (int rt = 0; rt < 4; ++rt) {
#pragma unroll
    for (int j = 0; j < 4; ++j) {
      const int r = (rt << 4) + (g << 2) + j;
      s_out[(size_t)(row0 + r) * K_CL + col] = st[rt][j] * rowinv[r];
    }
  }
  __syncthreads();

  // ---- numpy-fp32-emulating refinement for ambiguous rows (rare; verified r3).
  unsigned int na = amb_n;
  if (na == 0) return;
  if (na > BM) na = BM;
  float* zrow   = (float*)pool;          // 256 floats (overlays key region)
  float* stmp   = (float*)pool + 256;    // 128 floats
  float* csq_np = (float*)pool + 384;    // 128 floats
  if (tid < K_CL) csq_np[tid] = np_sumsq256(cen + (size_t)tid * D_DIM);
  for (unsigned int e = 0; e < na; ++e) {
    const int r = amb_rows[e];
    __syncthreads();   // csq_np ready / previous iteration's reads done
    if (tid < 64) {
      *(float4*)(zrow + tid * 4) =
          *(const float4*)(z + (size_t)(row0 + r) * D_DIM + tid * 4);
    }
    __syncthreads();
    if (tid == 0) zsq_np_sh = np_sumsq256(zrow);
    __syncthreads();
    if (tid < K_CL) {
      const float* crow = cen + (size_t)tid * D_DIM;
      double dacc = 0.0;
      for (int d = 0; d < D_DIM; ++d)
        dacc += (double)zrow[d] * (double)crow[d];
      {
#pragma clang fp contract(off)
        const float dotf = (float)dacc;                        // ~sgemm, CR
        const float sq   = (zsq_np_sh + csq_np[tid]) - 2.0f * dotf;
        const float nrm  = sqrtf(fmaxf(sq, 0.0f));
        stmp[tid] = 1.0f / (1.0f + nrm);                       // np pow -1 fast path
      }
    }
    __syncthreads();
    if (tid == 0) {
#pragma clang fp contract(off)
      const float sum = np_sum128(stmp);
      int best = 0;
      float bs = stmp[0] / sum;
      for (int i = 1; i < K_CL; ++i) {
        const float si = stmp[i] / sum;
        if (si > bs) { bs = si; best = i; }   // strict >: first-index wins ties
      }
      c_out[row0 + r] = (float)best;
    }
  }
}

extern "C" void kernel_launch(void* const* d_in, const int* in_sizes, int n_in,
                              void* d_out, int out_size, void* d_ws, size_t ws_size,
                              hipStream_t stream) {
  const float* z   = (const float*)d_in[0];
  const float* cen = (const float*)d_in[1];
  const int M = in_sizes[0] / D_DIM;   // 131072
  float* s_out = (float*)d_out;
  float* c_out = s_out + (size_t)M * K_CL;

  hipLaunchKernelGGL(k_main, dim3(M / BM), dim3(512), 0, stream,
                     z, cen, s_out, c_out);
}